// Round 3
// baseline (757.849 us; speedup 1.0000x reference)
//
#include <hip/hip_runtime.h>

// Problem constants: b=2, c=512, h=w=32, G=2, heads=8, ch=32, N=h*w*G=2048
#define QSZ 1048576              // 16 bh * 32 ch * 2048 n  (floats per Q/K/V/O array)
#define SMP 2052                 // padded row stride for score LDS (2048+4)
#define HSP 260                  // padded row stride for hist LDS (256+4)

__device__ __forceinline__ unsigned int ordf(float f) {
    unsigned int u = __float_as_uint(f);
    return u ^ ((u & 0x80000000u) ? 0xFFFFFFFFu : 0x80000000u);
}

// ---------------- Kernel A: pointwise group-mix + depthwise 3x3 conv --------
// grid: b(2) * o(6) * dd(256) = 3072 blocks, 256 threads
// writes: Q,K c-major [bh][chn][n]; V token-major [bh][n][chn]
__global__ void conv_qkv(const float* __restrict__ x, const float* __restrict__ wqkv,
                         const float* __restrict__ wdw, float* __restrict__ ws) {
    const int blk = blockIdx.x;
    const int b   = blk / 1536;
    const int rem = blk - b * 1536;
    const int o   = rem >> 8;
    const int dd  = rem & 255;
    const int tid = threadIdx.x;

    const float wq0 = wqkv[o * 2 + 0], wq1 = wqkv[o * 2 + 1];
    float wk[9];
#pragma unroll
    for (int i = 0; i < 9; ++i) wk[i] = wdw[o * 9 + i];

    __shared__ float T[34 * 34];
    const float* x0 = x + ((b * 2 + 0) * 256 + dd) * 1024;
    const float* x1 = x + ((b * 2 + 1) * 256 + dd) * 1024;
    for (int idx = tid; idx < 34 * 34; idx += 256) {
        const int yy = idx / 34 - 1;
        const int xx = idx % 34 - 1;
        float v = 0.f;
        if (yy >= 0 && yy < 32 && xx >= 0 && xx < 32)
            v = wq0 * x0[yy * 32 + xx] + wq1 * x1[yy * 32 + xx];
        T[idx] = v;
    }
    __syncthreads();

    const int g = o & 1;
    const int head = dd >> 5, chn = dd & 31;
    const int bh = b * 8 + head;
    float* Qp = ws + (bh * 32 + chn) * 2048;
    float* Kp = ws + QSZ + (bh * 32 + chn) * 2048;
    float* Vp = ws + 2 * QSZ + bh * 2048 * 32 + chn;

#pragma unroll
    for (int pp = 0; pp < 4; ++pp) {
        const int pix = tid + pp * 256;
        const int hh = pix >> 5, wx = pix & 31;
        float acc = 0.f;
#pragma unroll
        for (int ky = 0; ky < 3; ++ky)
#pragma unroll
            for (int kx = 0; kx < 3; ++kx)
                acc += wk[ky * 3 + kx] * T[(hh + ky) * 34 + wx + kx];
        const int n = pix * 2 + g;
        if (o < 2)      Qp[n] = acc;
        else if (o < 4) Kp[n] = acc;
        else            Vp[n * 32] = acc;
    }
}

// ---------------- Kernel B: per-(bh,ch) norm factors ------------------------
// wfac[bh*32+ch] = temperature[head] / (max(||q||,eps) * max(||k||,eps))
// grid: 512 blocks (bh*ch), 256 threads
__global__ void normfac(const float* __restrict__ tempr, float* __restrict__ ws) {
    const int row = blockIdx.x, tid = threadIdx.x;
    const float* qr = ws + row * 2048;
    const float* kr = ws + QSZ + row * 2048;
    float sq = 0.f, sk = 0.f;
    for (int i = tid * 4; i < 2048; i += 1024) {
        const float4 a = *reinterpret_cast<const float4*>(qr + i);
        const float4 c = *reinterpret_cast<const float4*>(kr + i);
        sq += a.x * a.x + a.y * a.y + a.z * a.z + a.w * a.w;
        sk += c.x * c.x + c.y * c.y + c.z * c.z + c.w * c.w;
    }
#pragma unroll
    for (int d = 32; d >= 1; d >>= 1) {
        sq += __shfl_xor(sq, d);
        sk += __shfl_xor(sk, d);
    }
    __shared__ float rq[4], rk[4];
    const int w = tid >> 6;
    if ((tid & 63) == 0) { rq[w] = sq; rk[w] = sk; }
    __syncthreads();
    if (tid == 0) {
        const float q = rq[0] + rq[1] + rq[2] + rq[3];
        const float k = rk[0] + rk[1] + rk[2] + rk[3];
        const float nq = fmaxf(sqrtf(q), 1e-12f);
        const float nk = fmaxf(sqrtf(k), 1e-12f);
        ws[4 * QSZ + row] = tempr[(row >> 5) & 7] / (nq * nk);
    }
}

// ---------------- Kernel C: scores + exact top-k(1024) + softmax + PV -------
// grid: bh(16) * ntile(256) = 4096 blocks, 256 threads; 8 query rows per block
__global__ __launch_bounds__(256) void attn_topk(float* __restrict__ ws) {
    const int tid = threadIdx.x;
    const int bh  = blockIdx.x >> 8;
    const int n0  = (blockIdx.x & 255) * 8;

    const float* __restrict__ Q  = ws;
    const float* __restrict__ K  = ws + QSZ;
    const float* __restrict__ V  = ws + 2 * QSZ;
    float* __restrict__ O        = ws + 3 * QSZ;
    const float* __restrict__ wf = ws + 4 * QSZ;

    __shared__ float sm[8 * SMP];          // scores -> p
    __shared__ float qT[32 * 8];           // [c][r], norm+temperature folded
    __shared__ unsigned int hist[8 * HSP];
    __shared__ float smaxs[8], invds[8];
    __shared__ unsigned int ctrlB[8], ctrlK[8];
    __shared__ float pr[4 * 8 * 33];       // PV partials [ms][r][c]

    // Phase 0: stage scaled q rows
    if (tid < 32) {
        const float w = wf[bh * 32 + tid];
        const float* qp = Q + (bh * 32 + tid) * 2048 + n0;
#pragma unroll
        for (int r = 0; r < 8; ++r) qT[tid * 8 + r] = qp[r] * w;
    }
    __syncthreads();

    // Phase 1: scores sm[r][m] = sum_c qT[c][r] * K[c][m]
    {
        const int rg  = tid >> 6;   // wave id 0..3 -> rows 2rg, 2rg+1
        const int col = tid & 63;   // 4 m's per thread per chunk
        const float* Kb = K + bh * 32 * 2048;
        for (int chk = 0; chk < 8; ++chk) {
            const int mb = chk * 256 + col * 4;
            float a00 = 0, a01 = 0, a02 = 0, a03 = 0;
            float a10 = 0, a11 = 0, a12 = 0, a13 = 0;
#pragma unroll 8
            for (int c = 0; c < 32; ++c) {
                const float4 k4 = *reinterpret_cast<const float4*>(Kb + c * 2048 + mb);
                const float q0 = qT[c * 8 + 2 * rg];
                const float q1 = qT[c * 8 + 2 * rg + 1];
                a00 += q0 * k4.x; a01 += q0 * k4.y; a02 += q0 * k4.z; a03 += q0 * k4.w;
                a10 += q1 * k4.x; a11 += q1 * k4.y; a12 += q1 * k4.z; a13 += q1 * k4.w;
            }
            *reinterpret_cast<float4*>(&sm[(2 * rg) * SMP + mb])     = make_float4(a00, a01, a02, a03);
            *reinterpret_cast<float4*>(&sm[(2 * rg + 1) * SMP + mb]) = make_float4(a10, a11, a12, a13);
        }
    }
    __syncthreads();

    // Phases 2+3: per 32-lane group (one query row): radix-256 select of the
    // 1024th-largest value, then p = exp(s - max) for kept, denom.
    {
        const int r    = tid >> 5;
        const int lane = tid & 31;
        unsigned int pref  = 0;
        unsigned int kkrem = 1024;
        float mx = -3.4e38f;
#pragma unroll 1
        for (int pass = 0; pass < 4; ++pass) {
            const int shift = 24 - pass * 8;
            *reinterpret_cast<uint4*>(&hist[r * HSP + lane * 8])     = make_uint4(0, 0, 0, 0);
            *reinterpret_cast<uint4*>(&hist[r * HSP + lane * 8 + 4]) = make_uint4(0, 0, 0, 0);
            __syncthreads();
            for (int j = 0; j < 64; ++j) {
                const float f = sm[r * SMP + lane + 32 * j];
                const unsigned int u = ordf(f);
                if (pass == 0) mx = fmaxf(mx, f);
                bool ok = true;
                if (pass > 0) ok = ((u >> (shift + 8)) == (pref >> (shift + 8)));
                if (ok) atomicAdd(&hist[r * HSP + ((u >> shift) & 255u)], 1u);
            }
            if (pass == 0) {
                float m2 = mx;
#pragma unroll
                for (int d = 16; d >= 1; d >>= 1) m2 = fmaxf(m2, __shfl_xor(m2, d, 32));
                if (lane == 0) smaxs[r] = m2;
            }
            __syncthreads();
            // suffix scan over 256 bins: lane owns bins [8*lane, 8*lane+7]
            const uint4 h0 = *reinterpret_cast<const uint4*>(&hist[r * HSP + lane * 8]);
            const uint4 h1 = *reinterpret_cast<const uint4*>(&hist[r * HSP + lane * 8 + 4]);
            const unsigned int h[8] = {h0.x, h0.y, h0.z, h0.w, h1.x, h1.y, h1.z, h1.w};
            unsigned int ls[8];
            ls[7] = h[7];
#pragma unroll
            for (int i = 6; i >= 0; --i) ls[i] = ls[i + 1] + h[i];
            unsigned int suf = ls[0];
#pragma unroll
            for (int d = 1; d < 32; d <<= 1) {
                const unsigned int t = __shfl_down(suf, d, 32);
                if (lane + d < 32) suf += t;
            }
            const unsigned int cum_above = suf - ls[0];
#pragma unroll
            for (int i = 7; i >= 0; --i) {
                const unsigned int cge = cum_above + ls[i];   // count in bins >= this bin
                const unsigned int cgt = cge - h[i];          // count in bins  > this bin
                if (cge >= kkrem && cgt < kkrem) {
                    ctrlB[r] = (unsigned int)(lane * 8 + i);
                    ctrlK[r] = kkrem - cgt;
                }
            }
            __syncthreads();
            pref |= ctrlB[r] << shift;
            kkrem = ctrlK[r];
            __syncthreads();
        }
        // pref == exact bit pattern (ordered space) of the kth-largest score
        const float m = smaxs[r];
        float dsum = 0.f;
        for (int j = 0; j < 64; ++j) {
            const int idx = r * SMP + lane + 32 * j;
            const float f = sm[idx];
            const float p = (ordf(f) >= pref) ? __expf(f - m) : 0.f;
            sm[idx] = p;
            dsum += p;
        }
#pragma unroll
        for (int d = 16; d >= 1; d >>= 1) dsum += __shfl_xor(dsum, d, 32);
        if (lane == 0) invds[r] = 1.f / dsum;
    }
    __syncthreads();

    // Phase 4: PV — out[r][c] = sum_m p[r][m] * V[m][c]
    {
        const int cg = tid & 7;          // 4 channels
        const int r8 = (tid >> 3) & 7;   // row
        const int ms = tid >> 6;         // m-split (wave)
        const float* Vb = V + bh * 2048 * 32;
        float ax = 0, ay = 0, az = 0, aw = 0;
        for (int mm = ms; mm < 512; mm += 4) {
            const float4 p4 = *reinterpret_cast<const float4*>(&sm[r8 * SMP + mm * 4]);
            const float* vb = Vb + mm * 128 + cg * 4;
            const float4 v0 = *reinterpret_cast<const float4*>(vb);
            const float4 v1 = *reinterpret_cast<const float4*>(vb + 32);
            const float4 v2 = *reinterpret_cast<const float4*>(vb + 64);
            const float4 v3 = *reinterpret_cast<const float4*>(vb + 96);
            ax += p4.x * v0.x + p4.y * v1.x + p4.z * v2.x + p4.w * v3.x;
            ay += p4.x * v0.y + p4.y * v1.y + p4.z * v2.y + p4.w * v3.y;
            az += p4.x * v0.z + p4.y * v1.z + p4.z * v2.z + p4.w * v3.z;
            aw += p4.x * v0.w + p4.y * v1.w + p4.z * v2.w + p4.w * v3.w;
        }
        float* prp = &pr[(ms * 8 + r8) * 33 + cg * 4];
        prp[0] = ax; prp[1] = ay; prp[2] = az; prp[3] = aw;
    }
    __syncthreads();
    {
        const int rr = tid >> 5, cc = tid & 31;
        const float o = (pr[(0 * 8 + rr) * 33 + cc] + pr[(1 * 8 + rr) * 33 + cc] +
                         pr[(2 * 8 + rr) * 33 + cc] + pr[(3 * 8 + rr) * 33 + cc]) * invds[rr];
        O[(bh * 2048 + n0 + rr) * 32 + cc] = o;
    }
}

// ---------------- Kernel D: output projection (512x512 GEMM per batch) ------
// grid: b(2) * otile(8) * stile(8) = 128 blocks, 256 threads; 64o x 128s tile
__global__ __launch_bounds__(256) void proj_out(const float* __restrict__ wproj,
                                                const float* __restrict__ ws,
                                                float* __restrict__ out) {
    const int tid = threadIdx.x;
    const int blk = blockIdx.x;
    const int st = blk & 7;
    const int ot = (blk >> 3) & 7;
    const int b  = blk >> 6;
    const int sbase = st * 128, obase = ot * 64;
    const float* O = ws + 3 * QSZ;

    __shared__ float At[32 * 132];   // [chn][s]
    __shared__ float Wt[32 * 68];    // [chn][o]

    float acc[4][8];
#pragma unroll
    for (int i = 0; i < 4; ++i)
#pragma unroll
        for (int j = 0; j < 8; ++j) acc[i][j] = 0.f;

    const int og = tid >> 4, sg = tid & 15;

    for (int cb = 0; cb < 16; ++cb) {     // c' block: c' = cb*32 + chn
        const int g = cb >> 3, head = cb & 7, bh = b * 8 + head;
        {   // stage A^T: A[c'][s] = O[bh][2s+g][chn]
            const int ss = tid >> 1, half = tid & 1;
            const float* op = O + ((bh * 2048) + (sbase + ss) * 2 + g) * 32 + half * 16;
#pragma unroll
            for (int j = 0; j < 4; ++j) {
                const float4 v = *reinterpret_cast<const float4*>(op + 4 * j);
                At[(half * 16 + 4 * j + 0) * 132 + ss] = v.x;
                At[(half * 16 + 4 * j + 1) * 132 + ss] = v.y;
                At[(half * 16 + 4 * j + 2) * 132 + ss] = v.z;
                At[(half * 16 + 4 * j + 3) * 132 + ss] = v.w;
            }
        }
        {   // stage W^T
            const int oo = tid >> 2, q = tid & 3;
#pragma unroll
            for (int jj = 0; jj < 2; ++jj) {
                const int chn = q * 8 + jj * 4;
                const float4 v = *reinterpret_cast<const float4*>(
                    wproj + (obase + oo) * 512 + cb * 32 + chn);
                Wt[(chn + 0) * 68 + oo] = v.x;
                Wt[(chn + 1) * 68 + oo] = v.y;
                Wt[(chn + 2) * 68 + oo] = v.z;
                Wt[(chn + 3) * 68 + oo] = v.w;
            }
        }
        __syncthreads();
#pragma unroll 8
        for (int chn = 0; chn < 32; ++chn) {
            const float4 wv = *reinterpret_cast<const float4*>(&Wt[chn * 68 + og * 4]);
            const float4 a0 = *reinterpret_cast<const float4*>(&At[chn * 132 + sg * 8]);
            const float4 a1 = *reinterpret_cast<const float4*>(&At[chn * 132 + sg * 8 + 4]);
            const float wj[4] = {wv.x, wv.y, wv.z, wv.w};
            const float aj[8] = {a0.x, a0.y, a0.z, a0.w, a1.x, a1.y, a1.z, a1.w};
#pragma unroll
            for (int i = 0; i < 4; ++i)
#pragma unroll
                for (int j = 0; j < 8; ++j) acc[i][j] += wj[i] * aj[j];
        }
        __syncthreads();
    }
#pragma unroll
    for (int i = 0; i < 4; ++i) {
        float* dst = out + (b * 512 + obase + og * 4 + i) * 1024 + sbase + sg * 8;
        *reinterpret_cast<float4*>(dst)     = make_float4(acc[i][0], acc[i][1], acc[i][2], acc[i][3]);
        *reinterpret_cast<float4*>(dst + 4) = make_float4(acc[i][4], acc[i][5], acc[i][6], acc[i][7]);
    }
}

extern "C" void kernel_launch(void* const* d_in, const int* in_sizes, int n_in,
                              void* d_out, int out_size, void* d_ws, size_t ws_size,
                              hipStream_t stream) {
    (void)in_sizes; (void)n_in; (void)out_size; (void)ws_size;
    const float* x     = (const float*)d_in[0];
    const float* wqkv  = (const float*)d_in[1];
    const float* wdw   = (const float*)d_in[2];
    const float* wproj = (const float*)d_in[3];
    const float* tempr = (const float*)d_in[4];
    float* ws  = (float*)d_ws;    // needs (4*QSZ + 512)*4B ~= 16.8 MB
    float* out = (float*)d_out;

    conv_qkv<<<3072, 256, 0, stream>>>(x, wqkv, wdw, ws);
    normfac<<<512, 256, 0, stream>>>(tempr, ws);
    attn_topk<<<4096, 256, 0, stream>>>(ws);
    proj_out<<<128, 256, 0, stream>>>(wproj, ws, out);
}

// Round 6
// 591.219 us; speedup vs baseline: 1.2818x; 1.2818x over previous
//
#include <hip/hip_runtime.h>
#include <hip/hip_fp16.h>

// Problem constants: b=2, c=512, h=w=32, G=2, heads=8, ch=32, N=h*w*G=2048
#define QSZ 1048576              // 16 bh * 32 ch * 2048 n  (floats per Q/K/V/O array)

__device__ __forceinline__ unsigned int ordf(float f) {
    unsigned int u = __float_as_uint(f);
    return u ^ ((u & 0x80000000u) ? 0xFFFFFFFFu : 0x80000000u);
}

// ---------------- Kernel A: pointwise group-mix + depthwise 3x3 conv --------
// grid: b(2) * o(6) * dd(256) = 3072 blocks, 256 threads
// writes: Q,K c-major [bh][chn][n]; V token-major [bh][n][chn]
__global__ void conv_qkv(const float* __restrict__ x, const float* __restrict__ wqkv,
                         const float* __restrict__ wdw, float* __restrict__ ws) {
    const int blk = blockIdx.x;
    const int b   = blk / 1536;
    const int rem = blk - b * 1536;
    const int o   = rem >> 8;
    const int dd  = rem & 255;
    const int tid = threadIdx.x;

    const float wq0 = wqkv[o * 2 + 0], wq1 = wqkv[o * 2 + 1];
    float wk[9];
#pragma unroll
    for (int i = 0; i < 9; ++i) wk[i] = wdw[o * 9 + i];

    __shared__ float T[34 * 34];
    const float* x0 = x + ((b * 2 + 0) * 256 + dd) * 1024;
    const float* x1 = x + ((b * 2 + 1) * 256 + dd) * 1024;
    for (int idx = tid; idx < 34 * 34; idx += 256) {
        const int yy = idx / 34 - 1;
        const int xx = idx % 34 - 1;
        float v = 0.f;
        if (yy >= 0 && yy < 32 && xx >= 0 && xx < 32)
            v = wq0 * x0[yy * 32 + xx] + wq1 * x1[yy * 32 + xx];
        T[idx] = v;
    }
    __syncthreads();

    const int g = o & 1;
    const int head = dd >> 5, chn = dd & 31;
    const int bh = b * 8 + head;
    float* Qp = ws + (bh * 32 + chn) * 2048;
    float* Kp = ws + QSZ + (bh * 32 + chn) * 2048;
    float* Vp = ws + 2 * QSZ + bh * 2048 * 32 + chn;

#pragma unroll
    for (int pp = 0; pp < 4; ++pp) {
        const int pix = tid + pp * 256;
        const int hh = pix >> 5, wx = pix & 31;
        float acc = 0.f;
#pragma unroll
        for (int ky = 0; ky < 3; ++ky)
#pragma unroll
            for (int kx = 0; kx < 3; ++kx)
                acc += wk[ky * 3 + kx] * T[(hh + ky) * 34 + wx + kx];
        const int n = pix * 2 + g;
        if (o < 2)      Qp[n] = acc;
        else if (o < 4) Kp[n] = acc;
        else            Vp[n * 32] = acc;
    }
}

// ---------------- Kernel B: per-(bh,ch) norm factors ------------------------
// wfac[bh*32+ch] = temperature[head] / (max(||q||,eps) * max(||k||,eps))
__global__ void normfac(const float* __restrict__ tempr, float* __restrict__ ws) {
    const int row = blockIdx.x, tid = threadIdx.x;
    const float* qr = ws + row * 2048;
    const float* kr = ws + QSZ + row * 2048;
    float sq = 0.f, sk = 0.f;
    for (int i = tid * 4; i < 2048; i += 1024) {
        const float4 a = *reinterpret_cast<const float4*>(qr + i);
        const float4 c = *reinterpret_cast<const float4*>(kr + i);
        sq += a.x * a.x + a.y * a.y + a.z * a.z + a.w * a.w;
        sk += c.x * c.x + c.y * c.y + c.z * c.z + c.w * c.w;
    }
#pragma unroll
    for (int d = 32; d >= 1; d >>= 1) {
        sq += __shfl_xor(sq, d);
        sk += __shfl_xor(sk, d);
    }
    __shared__ float rq[4], rk[4];
    const int w = tid >> 6;
    if ((tid & 63) == 0) { rq[w] = sq; rk[w] = sk; }
    __syncthreads();
    if (tid == 0) {
        const float q = rq[0] + rq[1] + rq[2] + rq[3];
        const float k = rk[0] + rk[1] + rk[2] + rk[3];
        const float nq = fmaxf(sqrtf(q), 1e-12f);
        const float nk = fmaxf(sqrtf(k), 1e-12f);
        ws[4 * QSZ + row] = tempr[(row >> 5) & 7] / (nq * nk);
    }
}

// ---------------- Kernel C: scores + exact top-k(1024) + softmax + PV -------
// Wave-per-row: 4 query rows per block (one per wave), scores live in VGPRs.
// Radix select: wave-private LDS histogram guarded by __syncthreads (same
// sync structure as the verified R3 kernel); the selected (bin,knew) is
// broadcast via a register shuffle OR-reduce (no LDS control words).
// grid: bh(16) * ntile(512) = 8192 blocks, 256 threads
__global__ __launch_bounds__(256, 4) void attn_topk(float* __restrict__ ws) {
    const int tid  = threadIdx.x;
    const int wv   = tid >> 6;      // wave id = query row 0..3
    const int lane = tid & 63;
    const int bh   = blockIdx.x >> 9;
    const int n0   = (blockIdx.x & 511) * 4;

    const float* __restrict__ Q  = ws;
    const float* __restrict__ K  = ws + QSZ;
    const float* __restrict__ V  = ws + 2 * QSZ;
    float* __restrict__ O        = ws + 3 * QSZ;
    const float* __restrict__ wf = ws + 4 * QSZ;

    __shared__ __half smh[4][2064];          // p rows (fp16), padded stride
    __shared__ float qT[32 * 4];             // [c][r], norm+temp folded
    __shared__ unsigned int hist[4][256];    // wave-private radix histograms
    __shared__ float invds[4];
    __shared__ float pr[8][4][33];           // PV partials [ms][r][c]

    // Phase 0: stage scaled q (4 rows x 32 ch)
    if (tid < 32) {
        const float w = wf[bh * 32 + tid];
        const float* qp = Q + (bh * 32 + tid) * 2048 + n0;
#pragma unroll
        for (int r = 0; r < 4; ++r) qT[tid * 4 + r] = qp[r] * w;
    }
    __syncthreads();

    // Phase 1: wave wv computes its full score row into registers.
    // lane owns m = g*256 + lane*4 + j  (j=0..3, g=0..7)
    float s[32];
#pragma unroll
    for (int i = 0; i < 32; ++i) s[i] = 0.f;
    {
        const float* Kb = K + bh * 32 * 2048 + (lane << 2);
        for (int c = 0; c < 32; ++c) {
            const float qv = qT[c * 4 + wv];          // LDS broadcast
            const float* kc = Kb + c * 2048;
#pragma unroll
            for (int g = 0; g < 8; ++g) {
                const float4 k4 = *reinterpret_cast<const float4*>(kc + g * 256);
                s[g * 4 + 0] += qv * k4.x;
                s[g * 4 + 1] += qv * k4.y;
                s[g * 4 + 2] += qv * k4.z;
                s[g * 4 + 3] += qv * k4.w;
            }
        }
    }

    // row max (wave-wide)
    float mx = s[0];
#pragma unroll
    for (int i = 1; i < 32; ++i) mx = fmaxf(mx, s[i]);
#pragma unroll
    for (int d = 32; d >= 1; d >>= 1) mx = fmaxf(mx, __shfl_xor(mx, d, 64));

    // Phase 2: exact radix-256 select of the 1024th-largest.
    unsigned int pref = 0, kkrem = 1024;
#pragma unroll 1
    for (int pass = 0; pass < 4; ++pass) {
        const int shift = 24 - pass * 8;
        *reinterpret_cast<uint4*>(&hist[wv][lane * 4]) = make_uint4(0, 0, 0, 0);
        __syncthreads();
#pragma unroll
        for (int i = 0; i < 32; ++i) {
            const unsigned int u = ordf(s[i]);
            const bool ok = (pass == 0) || ((u >> (shift + 8)) == (pref >> (shift + 8)));
            if (ok) atomicAdd(&hist[wv][(u >> shift) & 255u], 1u);
        }
        __syncthreads();
        const uint4 hv = *reinterpret_cast<const uint4*>(&hist[wv][lane * 4]);
        const unsigned int h[4] = {hv.x, hv.y, hv.z, hv.w};
        unsigned int ls[4];
        ls[3] = h[3];
#pragma unroll
        for (int i = 2; i >= 0; --i) ls[i] = ls[i + 1] + h[i];
        unsigned int suf = ls[0];
#pragma unroll
        for (int d = 1; d < 64; d <<= 1) {
            const unsigned int t = __shfl_down(suf, d, 64);
            if (lane + d < 64) suf += t;
        }
        const unsigned int cum_above = suf - ls[0];
        unsigned int sel = 0;
#pragma unroll
        for (int i = 3; i >= 0; --i) {
            const unsigned int cge = cum_above + ls[i];   // count in bins >= i
            const unsigned int cgt = cge - h[i];          // count in bins  > i
            if (cge >= kkrem && cgt < kkrem)
                sel = (unsigned int)(lane * 4 + i) | ((kkrem - cgt) << 8);
        }
        // exactly one lane has sel != 0 -> OR-reduce broadcasts to all lanes
#pragma unroll
        for (int d = 1; d < 64; d <<= 1) sel |= __shfl_xor(sel, d, 64);
        pref |= (sel & 255u) << shift;
        kkrem = sel >> 8;
    }

    // Phase 3: p = exp(s - max) for kept; fp16 round-trip so the denominator
    // matches the PV numerator exactly; wave-reduce denom.
    float dsum = 0.f;
#pragma unroll
    for (int g = 0; g < 8; ++g) {
        float p[4];
#pragma unroll
        for (int j = 0; j < 4; ++j) {
            const float f = s[g * 4 + j];
            p[j] = (ordf(f) >= pref) ? __expf(f - mx) : 0.f;
        }
        const __half2 h01 = __floats2half2_rn(p[0], p[1]);
        const __half2 h23 = __floats2half2_rn(p[2], p[3]);
        const float2 q01 = __half22float2(h01);
        const float2 q23 = __half22float2(h23);
        dsum += (q01.x + q01.y) + (q23.x + q23.y);
        uint2 u;
        u.x = *reinterpret_cast<const unsigned int*>(&h01);
        u.y = *reinterpret_cast<const unsigned int*>(&h23);
        *reinterpret_cast<uint2*>(&smh[wv][g * 256 + lane * 4]) = u;
    }
#pragma unroll
    for (int d = 32; d >= 1; d >>= 1) dsum += __shfl_xor(dsum, d, 64);
    if (lane == 0) invds[wv] = 1.f / dsum;
    __syncthreads();

    // Phase 4: PV — out[r][c] = sum_m p[r][m] * V[m][c]
    {
        const int cg = tid & 7;          // 4 channels: c = cg*4
        const int r4 = (tid >> 3) & 3;   // row
        const int ms = tid >> 5;         // m-split 0..7
        const float* Vb = V + bh * 2048 * 32;
        float ax = 0, ay = 0, az = 0, aw = 0;
        for (int mm = ms; mm < 512; mm += 8) {
            const uint2 pu = *reinterpret_cast<const uint2*>(&smh[r4][mm * 4]);
            const float2 p01 = __half22float2(*reinterpret_cast<const __half2*>(&pu.x));
            const float2 p23 = __half22float2(*reinterpret_cast<const __half2*>(&pu.y));
            const float* vb = Vb + mm * 128 + cg * 4;
            const float4 v0 = *reinterpret_cast<const float4*>(vb);
            const float4 v1 = *reinterpret_cast<const float4*>(vb + 32);
            const float4 v2 = *reinterpret_cast<const float4*>(vb + 64);
            const float4 v3 = *reinterpret_cast<const float4*>(vb + 96);
            ax += p01.x * v0.x + p01.y * v1.x + p23.x * v2.x + p23.y * v3.x;
            ay += p01.x * v0.y + p01.y * v1.y + p23.x * v2.y + p23.y * v3.y;
            az += p01.x * v0.z + p01.y * v1.z + p23.x * v2.z + p23.y * v3.z;
            aw += p01.x * v0.w + p01.y * v1.w + p23.x * v2.w + p23.y * v3.w;
        }
        float* prp = &pr[ms][r4][cg * 4];
        prp[0] = ax; prp[1] = ay; prp[2] = az; prp[3] = aw;
    }
    __syncthreads();
    if (tid < 128) {
        const int rr = tid >> 5, cc = tid & 31;
        float o = 0.f;
#pragma unroll
        for (int m = 0; m < 8; ++m) o += pr[m][rr][cc];
        O[(bh * 2048 + n0 + rr) * 32 + cc] = o * invds[rr];
    }
}

// ---------------- Kernel D: output projection (512x512 GEMM per batch) ------
__global__ __launch_bounds__(256) void proj_out(const float* __restrict__ wproj,
                                                const float* __restrict__ ws,
                                                float* __restrict__ out) {
    const int tid = threadIdx.x;
    const int blk = blockIdx.x;
    const int st = blk & 7;
    const int ot = (blk >> 3) & 7;
    const int b  = blk >> 6;
    const int sbase = st * 128, obase = ot * 64;
    const float* O = ws + 3 * QSZ;

    __shared__ float At[32 * 132];   // [chn][s]
    __shared__ float Wt[32 * 68];    // [chn][o]

    float acc[4][8];
#pragma unroll
    for (int i = 0; i < 4; ++i)
#pragma unroll
        for (int j = 0; j < 8; ++j) acc[i][j] = 0.f;

    const int og = tid >> 4, sg = tid & 15;

    for (int cb = 0; cb < 16; ++cb) {     // c' block: c' = cb*32 + chn
        const int g = cb >> 3, head = cb & 7, bh = b * 8 + head;
        {   // stage A^T: A[c'][s] = O[bh][2s+g][chn]
            const int ss = tid >> 1, half = tid & 1;
            const float* op = O + ((bh * 2048) + (sbase + ss) * 2 + g) * 32 + half * 16;
#pragma unroll
            for (int j = 0; j < 4; ++j) {
                const float4 v = *reinterpret_cast<const float4*>(op + 4 * j);
                At[(half * 16 + 4 * j + 0) * 132 + ss] = v.x;
                At[(half * 16 + 4 * j + 1) * 132 + ss] = v.y;
                At[(half * 16 + 4 * j + 2) * 132 + ss] = v.z;
                At[(half * 16 + 4 * j + 3) * 132 + ss] = v.w;
            }
        }
        {   // stage W^T
            const int oo = tid >> 2, q = tid & 3;
#pragma unroll
            for (int jj = 0; jj < 2; ++jj) {
                const int chn = q * 8 + jj * 4;
                const float4 v = *reinterpret_cast<const float4*>(
                    wproj + (obase + oo) * 512 + cb * 32 + chn);
                Wt[(chn + 0) * 68 + oo] = v.x;
                Wt[(chn + 1) * 68 + oo] = v.y;
                Wt[(chn + 2) * 68 + oo] = v.z;
                Wt[(chn + 3) * 68 + oo] = v.w;
            }
        }
        __syncthreads();
#pragma unroll 8
        for (int chn = 0; chn < 32; ++chn) {
            const float4 wv = *reinterpret_cast<const float4*>(&Wt[chn * 68 + og * 4]);
            const float4 a0 = *reinterpret_cast<const float4*>(&At[chn * 132 + sg * 8]);
            const float4 a1 = *reinterpret_cast<const float4*>(&At[chn * 132 + sg * 8 + 4]);
            const float wj[4] = {wv.x, wv.y, wv.z, wv.w};
            const float aj[8] = {a0.x, a0.y, a0.z, a0.w, a1.x, a1.y, a1.z, a1.w};
#pragma unroll
            for (int i = 0; i < 4; ++i)
#pragma unroll
                for (int j = 0; j < 8; ++j) acc[i][j] += wj[i] * aj[j];
        }
        __syncthreads();
    }
#pragma unroll
    for (int i = 0; i < 4; ++i) {
        float* dst = out + (b * 512 + obase + og * 4 + i) * 1024 + sbase + sg * 8;
        *reinterpret_cast<float4*>(dst)     = make_float4(acc[i][0], acc[i][1], acc[i][2], acc[i][3]);
        *reinterpret_cast<float4*>(dst + 4) = make_float4(acc[i][4], acc[i][5], acc[i][6], acc[i][7]);
    }
}

extern "C" void kernel_launch(void* const* d_in, const int* in_sizes, int n_in,
                              void* d_out, int out_size, void* d_ws, size_t ws_size,
                              hipStream_t stream) {
    (void)in_sizes; (void)n_in; (void)out_size; (void)ws_size;
    const float* x     = (const float*)d_in[0];
    const float* wqkv  = (const float*)d_in[1];
    const float* wdw   = (const float*)d_in[2];
    const float* wproj = (const float*)d_in[3];
    const float* tempr = (const float*)d_in[4];
    float* ws  = (float*)d_ws;    // needs (4*QSZ + 512)*4B ~= 16.8 MB
    float* out = (float*)d_out;

    conv_qkv<<<3072, 256, 0, stream>>>(x, wqkv, wdw, ws);
    normfac<<<512, 256, 0, stream>>>(tempr, ws);
    attn_topk<<<8192, 256, 0, stream>>>(ws);
    proj_out<<<128, 256, 0, stream>>>(wproj, ws, out);
}

// Round 10
// 507.541 us; speedup vs baseline: 1.4932x; 1.1649x over previous
//
#include <hip/hip_runtime.h>
#include <hip/hip_fp16.h>

// Problem constants: b=2, c=512, h=w=32, G=2, heads=8, ch=32, N=h*w*G=2048
#define QSZ 1048576              // 16 bh * 32 ch * 2048 n  (floats per Q/K/V2/O array)

__device__ __forceinline__ unsigned int ordf(float f) {
    unsigned int u = __float_as_uint(f);
    return u ^ ((u & 0x80000000u) ? 0xFFFFFFFFu : 0x80000000u);
}

// ---------------- Kernel A: pointwise group-mix + depthwise 3x3 conv --------
// grid: b(2) * o(6) * dd(256) = 3072 blocks, 256 threads
// writes: Q, K, V2 all c-major [bh][chn][n]
__global__ void conv_qkv(const float* __restrict__ x, const float* __restrict__ wqkv,
                         const float* __restrict__ wdw, float* __restrict__ ws) {
    const int blk = blockIdx.x;
    const int b   = blk / 1536;
    const int rem = blk - b * 1536;
    const int o   = rem >> 8;
    const int dd  = rem & 255;
    const int tid = threadIdx.x;

    const float wq0 = wqkv[o * 2 + 0], wq1 = wqkv[o * 2 + 1];
    float wk[9];
#pragma unroll
    for (int i = 0; i < 9; ++i) wk[i] = wdw[o * 9 + i];

    __shared__ float T[34 * 34];
    const float* x0 = x + ((b * 2 + 0) * 256 + dd) * 1024;
    const float* x1 = x + ((b * 2 + 1) * 256 + dd) * 1024;
    for (int idx = tid; idx < 34 * 34; idx += 256) {
        const int yy = idx / 34 - 1;
        const int xx = idx % 34 - 1;
        float v = 0.f;
        if (yy >= 0 && yy < 32 && xx >= 0 && xx < 32)
            v = wq0 * x0[yy * 32 + xx] + wq1 * x1[yy * 32 + xx];
        T[idx] = v;
    }
    __syncthreads();

    const int g = o & 1;
    const int head = dd >> 5, chn = dd & 31;
    const int bh = b * 8 + head;
    float* Qp = ws + (bh * 32 + chn) * 2048;
    float* Kp = ws + QSZ + (bh * 32 + chn) * 2048;
    float* Vp = ws + 2 * QSZ + (bh * 32 + chn) * 2048;   // c-major V

#pragma unroll
    for (int pp = 0; pp < 4; ++pp) {
        const int pix = tid + pp * 256;
        const int hh = pix >> 5, wx = pix & 31;
        float acc = 0.f;
#pragma unroll
        for (int ky = 0; ky < 3; ++ky)
#pragma unroll
            for (int kx = 0; kx < 3; ++kx)
                acc += wk[ky * 3 + kx] * T[(hh + ky) * 34 + wx + kx];
        const int n = pix * 2 + g;
        if (o < 2)      Qp[n] = acc;
        else if (o < 4) Kp[n] = acc;
        else            Vp[n] = acc;
    }
}

// ---------------- Kernel B: per-(bh,ch) norm factors ------------------------
__global__ void normfac(const float* __restrict__ tempr, float* __restrict__ ws) {
    const int row = blockIdx.x, tid = threadIdx.x;
    const float* qr = ws + row * 2048;
    const float* kr = ws + QSZ + row * 2048;
    float sq = 0.f, sk = 0.f;
    for (int i = tid * 4; i < 2048; i += 1024) {
        const float4 a = *reinterpret_cast<const float4*>(qr + i);
        const float4 c = *reinterpret_cast<const float4*>(kr + i);
        sq += a.x * a.x + a.y * a.y + a.z * a.z + a.w * a.w;
        sk += c.x * c.x + c.y * c.y + c.z * c.z + c.w * c.w;
    }
#pragma unroll
    for (int d = 32; d >= 1; d >>= 1) {
        sq += __shfl_xor(sq, d);
        sk += __shfl_xor(sk, d);
    }
    __shared__ float rq[4], rk[4];
    const int w = tid >> 6;
    if ((tid & 63) == 0) { rq[w] = sq; rk[w] = sk; }
    __syncthreads();
    if (tid == 0) {
        const float q = rq[0] + rq[1] + rq[2] + rq[3];
        const float k = rk[0] + rk[1] + rk[2] + rk[3];
        const float nq = fmaxf(sqrtf(q), 1e-12f);
        const float nk = fmaxf(sqrtf(k), 1e-12f);
        ws[4 * QSZ + row] = tempr[(row >> 5) & 7] / (nq * nk);
    }
}

// reduce-scatter: input a[32] per lane (partial sums over that lane's m's);
// output: every lane returns total over all 64 lanes for channel c = lane&31.
__device__ __forceinline__ float rscat32(float (&a)[32], int lane) {
#pragma unroll
    for (int c = 0; c < 32; ++c) a[c] += __shfl_xor(a[c], 32, 64);
    float b16[16];
    {
        const bool hi = (lane & 16) != 0;
#pragma unroll
        for (int i = 0; i < 16; ++i) {
            const float keep = hi ? a[i + 16] : a[i];
            const float send = hi ? a[i] : a[i + 16];
            b16[i] = keep + __shfl_xor(send, 16, 64);
        }
    }
    float b8[8];
    {
        const bool hi = (lane & 8) != 0;
#pragma unroll
        for (int i = 0; i < 8; ++i) {
            const float keep = hi ? b16[i + 8] : b16[i];
            const float send = hi ? b16[i] : b16[i + 8];
            b8[i] = keep + __shfl_xor(send, 8, 64);
        }
    }
    float b4[4];
    {
        const bool hi = (lane & 4) != 0;
#pragma unroll
        for (int i = 0; i < 4; ++i) {
            const float keep = hi ? b8[i + 4] : b8[i];
            const float send = hi ? b8[i] : b8[i + 4];
            b4[i] = keep + __shfl_xor(send, 4, 64);
        }
    }
    float b2[2];
    {
        const bool hi = (lane & 2) != 0;
#pragma unroll
        for (int i = 0; i < 2; ++i) {
            const float keep = hi ? b4[i + 2] : b4[i];
            const float send = hi ? b4[i] : b4[i + 2];
            b2[i] = keep + __shfl_xor(send, 2, 64);
        }
    }
    const bool hi = (lane & 1) != 0;
    const float keep = hi ? b2[1] : b2[0];
    const float send = hi ? b2[0] : b2[1];
    return keep + __shfl_xor(send, 1, 64);
}

// ---------------- Kernel C: scores + exact top-k(1024) + softmax + PV -------
// 8 rows/block (2 per wave, register-blocked). K and V chunks (32ch x 256m,
// 32 KB) staged in LDS once per block and shared by all 4 waves -> per-row
// L2 traffic drops 512KB -> 64KB. p kept in registers (fp16-packed).
// XCD swizzle: all blocks of a bh land on XCD bh&7 (K/V stay L2-local).
// grid: 4096 blocks, 256 threads
__global__ __launch_bounds__(256, 3) void attn_topk(float* __restrict__ ws) {
    const int tid  = threadIdx.x;
    const int wv   = tid >> 6;      // wave id: owns local rows wv*2, wv*2+1
    const int lane = tid & 63;
    const int bid  = blockIdx.x;
    const int xcd  = bid & 7;
    const int jj   = bid >> 3;                 // 0..511
    const int bh   = ((jj & 1) << 3) | xcd;    // 0..15, pinned to XCD bh&7
    const int n0   = (jj >> 1) * 8;            // 8 rows per block

    const float* __restrict__ Q  = ws;
    const float* __restrict__ K  = ws + QSZ;
    const float* __restrict__ V  = ws + 2 * QSZ;   // c-major
    float* __restrict__ O        = ws + 3 * QSZ;
    const float* __restrict__ wf = ws + 4 * QSZ;

    __shared__ float buf[32 * 256];              // staged K/V chunk (32 KB)
    __shared__ float qT[32 * 8];                 // [c][local row]
    __shared__ unsigned int hist[4][2][256];     // per-wave, per-row radix hist

    // Phase 0: stage scaled q (32 ch x 8 rows), one element per thread
    {
        const int c = tid >> 3, lr = tid & 7;
        qT[c * 8 + lr] = Q[(bh * 32 + c) * 2048 + n0 + lr] * wf[bh * 32 + c];
    }

    float s0[32], s1[32];
#pragma unroll
    for (int i = 0; i < 32; ++i) { s0[i] = 0.f; s1[i] = 0.f; }

    const float* Kb = K + bh * 32 * 2048;
    const float* Vb = V + bh * 32 * 2048;

    // Phase 1: QK^T. lane owns m = g*256 + lane*4 + j for both of its rows.
#pragma unroll
    for (int g = 0; g < 8; ++g) {
        {   // stage chunk g of K: wave wv stages rows wv*8..wv*8+7
            const float* src = Kb + (wv * 8) * 2048 + g * 256 + lane * 4;
            float* dst = buf + (wv * 8) * 256 + lane * 4;
#pragma unroll
            for (int i = 0; i < 8; ++i)
                *reinterpret_cast<float4*>(dst + i * 256) =
                    *reinterpret_cast<const float4*>(src + i * 2048);
        }
        __syncthreads();
#pragma unroll
        for (int c = 0; c < 32; ++c) {
            const float2 q2 = *reinterpret_cast<const float2*>(&qT[c * 8 + wv * 2]);
            const float4 k4 = *reinterpret_cast<const float4*>(&buf[c * 256 + lane * 4]);
            s0[g * 4 + 0] += q2.x * k4.x; s0[g * 4 + 1] += q2.x * k4.y;
            s0[g * 4 + 2] += q2.x * k4.z; s0[g * 4 + 3] += q2.x * k4.w;
            s1[g * 4 + 0] += q2.y * k4.x; s1[g * 4 + 1] += q2.y * k4.y;
            s1[g * 4 + 2] += q2.y * k4.z; s1[g * 4 + 3] += q2.y * k4.w;
        }
        __syncthreads();
    }

    // row maxes (wave-wide)
    float mx0 = s0[0], mx1 = s1[0];
#pragma unroll
    for (int i = 1; i < 32; ++i) { mx0 = fmaxf(mx0, s0[i]); mx1 = fmaxf(mx1, s1[i]); }
#pragma unroll
    for (int d = 32; d >= 1; d >>= 1) {
        mx0 = fmaxf(mx0, __shfl_xor(mx0, d, 64));
        mx1 = fmaxf(mx1, __shfl_xor(mx1, d, 64));
    }

    // Phase 2: exact radix-256 select of the 1024th-largest, both rows at once.
    unsigned int pref0 = 0, kk0 = 1024, pref1 = 0, kk1 = 1024;
#pragma unroll 1
    for (int pass = 0; pass < 4; ++pass) {
        const int shift = 24 - pass * 8;
        *reinterpret_cast<uint4*>(&hist[wv][0][lane * 4]) = make_uint4(0, 0, 0, 0);
        *reinterpret_cast<uint4*>(&hist[wv][1][lane * 4]) = make_uint4(0, 0, 0, 0);
        __syncthreads();
#pragma unroll
        for (int i = 0; i < 32; ++i) {
            const unsigned int u0 = ordf(s0[i]);
            const bool ok0 = (pass == 0) || ((u0 >> (shift + 8)) == (pref0 >> (shift + 8)));
            if (ok0) atomicAdd(&hist[wv][0][(u0 >> shift) & 255u], 1u);
            const unsigned int u1 = ordf(s1[i]);
            const bool ok1 = (pass == 0) || ((u1 >> (shift + 8)) == (pref1 >> (shift + 8)));
            if (ok1) atomicAdd(&hist[wv][1][(u1 >> shift) & 255u], 1u);
        }
        __syncthreads();
        const uint4 h0v = *reinterpret_cast<const uint4*>(&hist[wv][0][lane * 4]);
        const uint4 h1v = *reinterpret_cast<const uint4*>(&hist[wv][1][lane * 4]);
        // pack both rows' counts: low16 = row0, high16 = row1 (counts <= 2048)
        unsigned int ph[4] = {h0v.x | (h1v.x << 16), h0v.y | (h1v.y << 16),
                              h0v.z | (h1v.z << 16), h0v.w | (h1v.w << 16)};
        unsigned int ls[4];
        ls[3] = ph[3];
#pragma unroll
        for (int i = 2; i >= 0; --i) ls[i] = ls[i + 1] + ph[i];
        unsigned int suf = ls[0];
#pragma unroll
        for (int d = 1; d < 64; d <<= 1) {
            const unsigned int t = __shfl_down(suf, d, 64);
            if (lane + d < 64) suf += t;
        }
        const unsigned int ca = suf - ls[0];     // packed count strictly above quad
        unsigned int sel0 = 0, sel1 = 0;
#pragma unroll
        for (int i = 3; i >= 0; --i) {
            const unsigned int cge0 = (ca & 0xffffu) + (ls[i] & 0xffffu);
            const unsigned int cgt0 = cge0 - (ph[i] & 0xffffu);
            if (cge0 >= kk0 && cgt0 < kk0)
                sel0 = (unsigned int)(lane * 4 + i) | ((kk0 - cgt0) << 8);
            const unsigned int cge1 = (ca >> 16) + (ls[i] >> 16);
            const unsigned int cgt1 = cge1 - (ph[i] >> 16);
            if (cge1 >= kk1 && cgt1 < kk1)
                sel1 = (unsigned int)(lane * 4 + i) | ((kk1 - cgt1) << 8);
        }
#pragma unroll
        for (int d = 1; d < 64; d <<= 1) {
            sel0 |= __shfl_xor(sel0, d, 64);
            sel1 |= __shfl_xor(sel1, d, 64);
        }
        pref0 |= (sel0 & 255u) << shift;  kk0 = sel0 >> 8;
        pref1 |= (sel1 & 255u) << shift;  kk1 = sel1 >> 8;
    }

    // Phase 3: p = exp(s - mx) for kept, packed fp16 in regs; f32 denom from
    // the round-tripped values (numerator == denominator weights exactly).
    unsigned int p0pk[16], p1pk[16];
    float ds0 = 0.f, ds1 = 0.f;
#pragma unroll
    for (int i2 = 0; i2 < 16; ++i2) {
        const float a0 = (ordf(s0[2 * i2])     >= pref0) ? __expf(s0[2 * i2]     - mx0) : 0.f;
        const float b0 = (ordf(s0[2 * i2 + 1]) >= pref0) ? __expf(s0[2 * i2 + 1] - mx0) : 0.f;
        __half2 h0 = __floats2half2_rn(a0, b0);
        p0pk[i2] = *reinterpret_cast<const unsigned int*>(&h0);
        const float2 q0 = __half22float2(h0);
        ds0 += q0.x + q0.y;
        const float a1 = (ordf(s1[2 * i2])     >= pref1) ? __expf(s1[2 * i2]     - mx1) : 0.f;
        const float b1 = (ordf(s1[2 * i2 + 1]) >= pref1) ? __expf(s1[2 * i2 + 1] - mx1) : 0.f;
        __half2 h1 = __floats2half2_rn(a1, b1);
        p1pk[i2] = *reinterpret_cast<const unsigned int*>(&h1);
        const float2 q1 = __half22float2(h1);
        ds1 += q1.x + q1.y;
    }
#pragma unroll
    for (int d = 32; d >= 1; d >>= 1) {
        ds0 += __shfl_xor(ds0, d, 64);
        ds1 += __shfl_xor(ds1, d, 64);
    }
    const float invd0 = 1.f / ds0, invd1 = 1.f / ds1;

    // Phase 4: PV from staged V chunks; acc[c] partial over this lane's m's.
    float acc0[32], acc1[32];
#pragma unroll
    for (int c = 0; c < 32; ++c) { acc0[c] = 0.f; acc1[c] = 0.f; }
#pragma unroll
    for (int g = 0; g < 8; ++g) {
        {   // stage chunk g of V (c-major, identical pattern to K)
            const float* src = Vb + (wv * 8) * 2048 + g * 256 + lane * 4;
            float* dst = buf + (wv * 8) * 256 + lane * 4;
#pragma unroll
            for (int i = 0; i < 8; ++i)
                *reinterpret_cast<float4*>(dst + i * 256) =
                    *reinterpret_cast<const float4*>(src + i * 2048);
        }
        __syncthreads();
        __half2 ha0 = *reinterpret_cast<const __half2*>(&p0pk[g * 2]);
        __half2 hb0 = *reinterpret_cast<const __half2*>(&p0pk[g * 2 + 1]);
        __half2 ha1 = *reinterpret_cast<const __half2*>(&p1pk[g * 2]);
        __half2 hb1 = *reinterpret_cast<const __half2*>(&p1pk[g * 2 + 1]);
        const float2 pa0 = __half22float2(ha0), pb0 = __half22float2(hb0);
        const float2 pa1 = __half22float2(ha1), pb1 = __half22float2(hb1);
#pragma unroll
        for (int c = 0; c < 32; ++c) {
            const float4 v4 = *reinterpret_cast<const float4*>(&buf[c * 256 + lane * 4]);
            acc0[c] += pa0.x * v4.x + pa0.y * v4.y + pb0.x * v4.z + pb0.y * v4.w;
            acc1[c] += pa1.x * v4.x + pa1.y * v4.y + pb1.x * v4.z + pb1.y * v4.w;
        }
        __syncthreads();
    }

    // Reduce-scatter across lanes -> lane holds channel c = lane&31; write O.
    const float o0 = rscat32(acc0, lane) * invd0;
    const float o1 = rscat32(acc1, lane) * invd1;
    const int r0 = n0 + wv * 2;
    if (lane < 32) {
        O[(bh * 2048 + r0) * 32 + lane]     = o0;
        O[(bh * 2048 + r0 + 1) * 32 + lane] = o1;
    }
}

// ---------------- Kernel D: output projection (512x512 GEMM per batch) ------
__global__ __launch_bounds__(256) void proj_out(const float* __restrict__ wproj,
                                                const float* __restrict__ ws,
                                                float* __restrict__ out) {
    const int tid = threadIdx.x;
    const int blk = blockIdx.x;
    const int st = blk & 7;
    const int ot = (blk >> 3) & 7;
    const int b  = blk >> 6;
    const int sbase = st * 128, obase = ot * 64;
    const float* O = ws + 3 * QSZ;

    __shared__ float At[32 * 132];   // [chn][s]
    __shared__ float Wt[32 * 68];    // [chn][o]

    float acc[4][8];
#pragma unroll
    for (int i = 0; i < 4; ++i)
#pragma unroll
        for (int j = 0; j < 8; ++j) acc[i][j] = 0.f;

    const int og = tid >> 4, sg = tid & 15;

    for (int cb = 0; cb < 16; ++cb) {     // c' block: c' = cb*32 + chn
        const int g = cb >> 3, head = cb & 7, bh = b * 8 + head;
        {   // stage A^T: A[c'][s] = O[bh][2s+g][chn]
            const int ss = tid >> 1, half = tid & 1;
            const float* op = O + ((bh * 2048) + (sbase + ss) * 2 + g) * 32 + half * 16;
#pragma unroll
            for (int j = 0; j < 4; ++j) {
                const float4 v = *reinterpret_cast<const float4*>(op + 4 * j);
                At[(half * 16 + 4 * j + 0) * 132 + ss] = v.x;
                At[(half * 16 + 4 * j + 1) * 132 + ss] = v.y;
                At[(half * 16 + 4 * j + 2) * 132 + ss] = v.z;
                At[(half * 16 + 4 * j + 3) * 132 + ss] = v.w;
            }
        }
        {   // stage W^T
            const int oo = tid >> 2, q = tid & 3;
#pragma unroll
            for (int jj = 0; jj < 2; ++jj) {
                const int chn = q * 8 + jj * 4;
                const float4 v = *reinterpret_cast<const float4*>(
                    wproj + (obase + oo) * 512 + cb * 32 + chn);
                Wt[(chn + 0) * 68 + oo] = v.x;
                Wt[(chn + 1) * 68 + oo] = v.y;
                Wt[(chn + 2) * 68 + oo] = v.z;
                Wt[(chn + 3) * 68 + oo] = v.w;
            }
        }
        __syncthreads();
#pragma unroll 8
        for (int chn = 0; chn < 32; ++chn) {
            const float4 wv = *reinterpret_cast<const float4*>(&Wt[chn * 68 + og * 4]);
            const float4 a0 = *reinterpret_cast<const float4*>(&At[chn * 132 + sg * 8]);
            const float4 a1 = *reinterpret_cast<const float4*>(&At[chn * 132 + sg * 8 + 4]);
            const float wj[4] = {wv.x, wv.y, wv.z, wv.w};
            const float aj[8] = {a0.x, a0.y, a0.z, a0.w, a1.x, a1.y, a1.z, a1.w};
#pragma unroll
            for (int i = 0; i < 4; ++i)
#pragma unroll
                for (int j = 0; j < 8; ++j) acc[i][j] += wj[i] * aj[j];
        }
        __syncthreads();
    }
#pragma unroll
    for (int i = 0; i < 4; ++i) {
        float* dst = out + (b * 512 + obase + og * 4 + i) * 1024 + sbase + sg * 8;
        *reinterpret_cast<float4*>(dst)     = make_float4(acc[i][0], acc[i][1], acc[i][2], acc[i][3]);
        *reinterpret_cast<float4*>(dst + 4) = make_float4(acc[i][4], acc[i][5], acc[i][6], acc[i][7]);
    }
}

extern "C" void kernel_launch(void* const* d_in, const int* in_sizes, int n_in,
                              void* d_out, int out_size, void* d_ws, size_t ws_size,
                              hipStream_t stream) {
    (void)in_sizes; (void)n_in; (void)out_size; (void)ws_size;
    const float* x     = (const float*)d_in[0];
    const float* wqkv  = (const float*)d_in[1];
    const float* wdw   = (const float*)d_in[2];
    const float* wproj = (const float*)d_in[3];
    const float* tempr = (const float*)d_in[4];
    float* ws  = (float*)d_ws;    // needs (4*QSZ + 512)*4B ~= 16.8 MB
    float* out = (float*)d_out;

    conv_qkv<<<3072, 256, 0, stream>>>(x, wqkv, wdw, ws);
    normfac<<<512, 256, 0, stream>>>(tempr, ws);
    attn_topk<<<4096, 256, 0, stream>>>(ws);
    proj_out<<<128, 256, 0, stream>>>(wproj, ws, out);
}

// Round 12
// 471.856 us; speedup vs baseline: 1.6061x; 1.0756x over previous
//
#include <hip/hip_runtime.h>
#include <hip/hip_fp16.h>

// Problem constants: b=2, c=512, h=w=32, G=2, heads=8, ch=32, N=h*w*G=2048
#define QSZ 1048576              // 16 bh * 32 ch * 2048 n  (floats per Q/K/V2/O array)

typedef _Float16 half2v __attribute__((ext_vector_type(2)));

__device__ __forceinline__ float fdot2u(unsigned int a, unsigned int b, float c) {
    return __builtin_amdgcn_fdot2(__builtin_bit_cast(half2v, a),
                                  __builtin_bit_cast(half2v, b), c, false);
}
__device__ __forceinline__ unsigned int ordf(float f) {
    unsigned int u = __float_as_uint(f);
    return u ^ ((u & 0x80000000u) ? 0xFFFFFFFFu : 0x80000000u);
}
__device__ __forceinline__ unsigned int pk_rn(float a, float b) {
    __half2 h = __floats2half2_rn(a, b);
    return *reinterpret_cast<const unsigned int*>(&h);
}

// ---------------- Kernel A: pointwise group-mix + depthwise 3x3 conv --------
// grid: b(2) * o(6) * dd(256) = 3072 blocks, 256 threads
// writes: Q, K, V2 all c-major [bh][chn][n]
__global__ void conv_qkv(const float* __restrict__ x, const float* __restrict__ wqkv,
                         const float* __restrict__ wdw, float* __restrict__ ws) {
    const int blk = blockIdx.x;
    const int b   = blk / 1536;
    const int rem = blk - b * 1536;
    const int o   = rem >> 8;
    const int dd  = rem & 255;
    const int tid = threadIdx.x;

    const float wq0 = wqkv[o * 2 + 0], wq1 = wqkv[o * 2 + 1];
    float wk[9];
#pragma unroll
    for (int i = 0; i < 9; ++i) wk[i] = wdw[o * 9 + i];

    __shared__ float T[34 * 34];
    const float* x0 = x + ((b * 2 + 0) * 256 + dd) * 1024;
    const float* x1 = x + ((b * 2 + 1) * 256 + dd) * 1024;
    for (int idx = tid; idx < 34 * 34; idx += 256) {
        const int yy = idx / 34 - 1;
        const int xx = idx % 34 - 1;
        float v = 0.f;
        if (yy >= 0 && yy < 32 && xx >= 0 && xx < 32)
            v = wq0 * x0[yy * 32 + xx] + wq1 * x1[yy * 32 + xx];
        T[idx] = v;
    }
    __syncthreads();

    const int g = o & 1;
    const int head = dd >> 5, chn = dd & 31;
    const int bh = b * 8 + head;
    float* Qp = ws + (bh * 32 + chn) * 2048;
    float* Kp = ws + QSZ + (bh * 32 + chn) * 2048;
    float* Vp = ws + 2 * QSZ + (bh * 32 + chn) * 2048;   // c-major V

#pragma unroll
    for (int pp = 0; pp < 4; ++pp) {
        const int pix = tid + pp * 256;
        const int hh = pix >> 5, wx = pix & 31;
        float acc = 0.f;
#pragma unroll
        for (int ky = 0; ky < 3; ++ky)
#pragma unroll
            for (int kx = 0; kx < 3; ++kx)
                acc += wk[ky * 3 + kx] * T[(hh + ky) * 34 + wx + kx];
        const int n = pix * 2 + g;
        if (o < 2)      Qp[n] = acc;
        else if (o < 4) Kp[n] = acc;
        else            Vp[n] = acc;
    }
}

// ---------------- Kernel B: per-(bh,ch) norm factors ------------------------
__global__ void normfac(const float* __restrict__ tempr, float* __restrict__ ws) {
    const int row = blockIdx.x, tid = threadIdx.x;
    const float* qr = ws + row * 2048;
    const float* kr = ws + QSZ + row * 2048;
    float sq = 0.f, sk = 0.f;
    for (int i = tid * 4; i < 2048; i += 1024) {
        const float4 a = *reinterpret_cast<const float4*>(qr + i);
        const float4 c = *reinterpret_cast<const float4*>(kr + i);
        sq += a.x * a.x + a.y * a.y + a.z * a.z + a.w * a.w;
        sk += c.x * c.x + c.y * c.y + c.z * c.z + c.w * c.w;
    }
#pragma unroll
    for (int d = 32; d >= 1; d >>= 1) {
        sq += __shfl_xor(sq, d);
        sk += __shfl_xor(sk, d);
    }
    __shared__ float rq[4], rk[4];
    const int w = tid >> 6;
    if ((tid & 63) == 0) { rq[w] = sq; rk[w] = sk; }
    __syncthreads();
    if (tid == 0) {
        const float q = rq[0] + rq[1] + rq[2] + rq[3];
        const float k = rk[0] + rk[1] + rk[2] + rk[3];
        const float nq = fmaxf(sqrtf(q), 1e-12f);
        const float nk = fmaxf(sqrtf(k), 1e-12f);
        ws[4 * QSZ + row] = tempr[(row >> 5) & 7] / (nq * nk);
    }
}

// reduce-scatter: input a[32] per lane (partial sums over that lane's m's);
// output: every lane returns total over all 64 lanes for channel c = lane&31.
__device__ __forceinline__ float rscat32(float (&a)[32], int lane) {
#pragma unroll
    for (int c = 0; c < 32; ++c) a[c] += __shfl_xor(a[c], 32, 64);
    float b16[16];
    {
        const bool hi = (lane & 16) != 0;
#pragma unroll
        for (int i = 0; i < 16; ++i) {
            const float keep = hi ? a[i + 16] : a[i];
            const float send = hi ? a[i] : a[i + 16];
            b16[i] = keep + __shfl_xor(send, 16, 64);
        }
    }
    float b8[8];
    {
        const bool hi = (lane & 8) != 0;
#pragma unroll
        for (int i = 0; i < 8; ++i) {
            const float keep = hi ? b16[i + 8] : b16[i];
            const float send = hi ? b16[i] : b16[i + 8];
            b8[i] = keep + __shfl_xor(send, 8, 64);
        }
    }
    float b4[4];
    {
        const bool hi = (lane & 4) != 0;
#pragma unroll
        for (int i = 0; i < 4; ++i) {
            const float keep = hi ? b8[i + 4] : b8[i];
            const float send = hi ? b8[i] : b8[i + 4];
            b4[i] = keep + __shfl_xor(send, 4, 64);
        }
    }
    float b2[2];
    {
        const bool hi = (lane & 2) != 0;
#pragma unroll
        for (int i = 0; i < 2; ++i) {
            const float keep = hi ? b4[i + 2] : b4[i];
            const float send = hi ? b4[i] : b4[i + 2];
            b2[i] = keep + __shfl_xor(send, 2, 64);
        }
    }
    const bool hi = (lane & 1) != 0;
    const float keep = hi ? b2[1] : b2[0];
    const float send = hi ? b2[0] : b2[1];
    return keep + __shfl_xor(send, 1, 64);
}

// ---------------- Kernel C: scores + exact top-k(1024) + softmax + PV -------
// 8 rows/block (2 per wave). Score path FULL f32 (exact R10 math: f32 K in
// LDS, f32 fma, exact 4-pass f32 radix select -> reference-matching top-k
// membership). Output path f16: V staged as rn-rounded f16 m-pairs (LDS
// bytes halve) and PV via v_dot2_f32_f16 against the fp16-packed p.
// grid: 4096 blocks, 256 threads
__global__ __launch_bounds__(256, 3) void attn_topk(float* __restrict__ ws) {
    const int tid  = threadIdx.x;
    const int wv   = tid >> 6;      // wave id: owns local rows wv*2, wv*2+1
    const int lane = tid & 63;
    const int bid  = blockIdx.x;
    const int xcd  = bid & 7;
    const int jj   = bid >> 3;                 // 0..511
    const int bh   = ((jj & 1) << 3) | xcd;    // 0..15, pinned to XCD bh&7
    const int n0   = (jj >> 1) * 8;            // 8 rows per block

    const float* __restrict__ Q  = ws;
    const float* __restrict__ K  = ws + QSZ;
    const float* __restrict__ V  = ws + 2 * QSZ;   // c-major
    float* __restrict__ O        = ws + 3 * QSZ;
    const float* __restrict__ wf = ws + 4 * QSZ;

    __shared__ float buf[32 * 256];              // K chunk f32 (32 KB); V aliases half
    __shared__ float qT[32 * 8];                 // [c][local row]
    __shared__ unsigned int hist[4][2][256];     // per-wave, per-row radix hist
    unsigned int* bufu = reinterpret_cast<unsigned int*>(buf);

    // Phase 0: stage scaled q (32 ch x 8 rows), one element per thread
    {
        const int c = tid >> 3, lr = tid & 7;
        qT[c * 8 + lr] = Q[(bh * 32 + c) * 2048 + n0 + lr] * wf[bh * 32 + c];
    }

    float s0[32], s1[32];
#pragma unroll
    for (int i = 0; i < 32; ++i) { s0[i] = 0.f; s1[i] = 0.f; }

    const float* Kb = K + bh * 32 * 2048;
    const float* Vb = V + bh * 32 * 2048;

    // Phase 1: QK^T (f32). lane owns m = g*256 + lane*4 + j for both rows.
#pragma unroll
    for (int g = 0; g < 8; ++g) {
        {   // stage chunk g of K: wave wv stages rows wv*8..wv*8+7
            const float* src = Kb + (wv * 8) * 2048 + g * 256 + lane * 4;
            float* dst = buf + (wv * 8) * 256 + lane * 4;
#pragma unroll
            for (int i = 0; i < 8; ++i)
                *reinterpret_cast<float4*>(dst + i * 256) =
                    *reinterpret_cast<const float4*>(src + i * 2048);
        }
        __syncthreads();
#pragma unroll
        for (int c = 0; c < 32; ++c) {
            const float2 q2 = *reinterpret_cast<const float2*>(&qT[c * 8 + wv * 2]);
            const float4 k4 = *reinterpret_cast<const float4*>(&buf[c * 256 + lane * 4]);
            s0[g * 4 + 0] += q2.x * k4.x; s0[g * 4 + 1] += q2.x * k4.y;
            s0[g * 4 + 2] += q2.x * k4.z; s0[g * 4 + 3] += q2.x * k4.w;
            s1[g * 4 + 0] += q2.y * k4.x; s1[g * 4 + 1] += q2.y * k4.y;
            s1[g * 4 + 2] += q2.y * k4.z; s1[g * 4 + 3] += q2.y * k4.w;
        }
        __syncthreads();
    }

    // row maxes (wave-wide)
    float mx0 = s0[0], mx1 = s1[0];
#pragma unroll
    for (int i = 1; i < 32; ++i) { mx0 = fmaxf(mx0, s0[i]); mx1 = fmaxf(mx1, s1[i]); }
#pragma unroll
    for (int d = 32; d >= 1; d >>= 1) {
        mx0 = fmaxf(mx0, __shfl_xor(mx0, d, 64));
        mx1 = fmaxf(mx1, __shfl_xor(mx1, d, 64));
    }

    // Phase 2: exact 4-pass radix-256 select of the 1024th-largest (f32 keys).
    unsigned int pref0 = 0, kk0 = 1024, pref1 = 0, kk1 = 1024;
#pragma unroll 1
    for (int pass = 0; pass < 4; ++pass) {
        const int shift = 24 - pass * 8;
        *reinterpret_cast<uint4*>(&hist[wv][0][lane * 4]) = make_uint4(0, 0, 0, 0);
        *reinterpret_cast<uint4*>(&hist[wv][1][lane * 4]) = make_uint4(0, 0, 0, 0);
        __syncthreads();
#pragma unroll
        for (int i = 0; i < 32; ++i) {
            const unsigned int u0 = ordf(s0[i]);
            const bool ok0 = (pass == 0) || ((u0 >> (shift + 8)) == (pref0 >> (shift + 8)));
            if (ok0) atomicAdd(&hist[wv][0][(u0 >> shift) & 255u], 1u);
            const unsigned int u1 = ordf(s1[i]);
            const bool ok1 = (pass == 0) || ((u1 >> (shift + 8)) == (pref1 >> (shift + 8)));
            if (ok1) atomicAdd(&hist[wv][1][(u1 >> shift) & 255u], 1u);
        }
        __syncthreads();
        const uint4 h0v = *reinterpret_cast<const uint4*>(&hist[wv][0][lane * 4]);
        const uint4 h1v = *reinterpret_cast<const uint4*>(&hist[wv][1][lane * 4]);
        // pack both rows' counts: low16 = row0, high16 = row1 (counts <= 2048)
        unsigned int ph[4] = {h0v.x | (h1v.x << 16), h0v.y | (h1v.y << 16),
                              h0v.z | (h1v.z << 16), h0v.w | (h1v.w << 16)};
        unsigned int ls[4];
        ls[3] = ph[3];
#pragma unroll
        for (int i = 2; i >= 0; --i) ls[i] = ls[i + 1] + ph[i];
        unsigned int suf = ls[0];
#pragma unroll
        for (int d = 1; d < 64; d <<= 1) {
            const unsigned int t = __shfl_down(suf, d, 64);
            if (lane + d < 64) suf += t;
        }
        const unsigned int ca = suf - ls[0];     // packed count strictly above quad
        unsigned int sel0 = 0, sel1 = 0;
#pragma unroll
        for (int i = 3; i >= 0; --i) {
            const unsigned int cge0 = (ca & 0xffffu) + (ls[i] & 0xffffu);
            const unsigned int cgt0 = cge0 - (ph[i] & 0xffffu);
            if (cge0 >= kk0 && cgt0 < kk0)
                sel0 = (unsigned int)(lane * 4 + i) | ((kk0 - cgt0) << 8);
            const unsigned int cge1 = (ca >> 16) + (ls[i] >> 16);
            const unsigned int cgt1 = cge1 - (ph[i] >> 16);
            if (cge1 >= kk1 && cgt1 < kk1)
                sel1 = (unsigned int)(lane * 4 + i) | ((kk1 - cgt1) << 8);
        }
#pragma unroll
        for (int d = 1; d < 64; d <<= 1) {
            sel0 |= __shfl_xor(sel0, d, 64);
            sel1 |= __shfl_xor(sel1, d, 64);
        }
        pref0 |= (sel0 & 255u) << shift;  kk0 = sel0 >> 8;
        pref1 |= (sel1 & 255u) << shift;  kk1 = sel1 >> 8;
    }

    // Phase 3: p = exp(s - mx) for kept, packed fp16 in regs; f32 denom from
    // the round-tripped values (numerator weights == denominator exactly).
    unsigned int p0pk[16], p1pk[16];
    float ds0 = 0.f, ds1 = 0.f;
#pragma unroll
    for (int i2 = 0; i2 < 16; ++i2) {
        const float a0 = (ordf(s0[2 * i2])     >= pref0) ? __expf(s0[2 * i2]     - mx0) : 0.f;
        const float b0 = (ordf(s0[2 * i2 + 1]) >= pref0) ? __expf(s0[2 * i2 + 1] - mx0) : 0.f;
        p0pk[i2] = pk_rn(a0, b0);
        const __half2 h0 = *reinterpret_cast<const __half2*>(&p0pk[i2]);
        const float2 q0 = __half22float2(h0);
        ds0 += q0.x + q0.y;
        const float a1 = (ordf(s1[2 * i2])     >= pref1) ? __expf(s1[2 * i2]     - mx1) : 0.f;
        const float b1 = (ordf(s1[2 * i2 + 1]) >= pref1) ? __expf(s1[2 * i2 + 1] - mx1) : 0.f;
        p1pk[i2] = pk_rn(a1, b1);
        const __half2 h1 = *reinterpret_cast<const __half2*>(&p1pk[i2]);
        const float2 q1 = __half22float2(h1);
        ds1 += q1.x + q1.y;
    }
#pragma unroll
    for (int d = 32; d >= 1; d >>= 1) {
        ds0 += __shfl_xor(ds0, d, 64);
        ds1 += __shfl_xor(ds1, d, 64);
    }
    const float invd0 = 1.f / ds0, invd1 = 1.f / ds1;

    // Phase 4: PV via dot2 from f16 m-pair-packed V chunks (output-side f16:
    // bounded perturbation of a convex combination, ~1e-4 in the output).
    float acc0[32], acc1[32];
#pragma unroll
    for (int c = 0; c < 32; ++c) { acc0[c] = 0.f; acc1[c] = 0.f; }
#pragma unroll 1
    for (int g = 0; g < 8; ++g) {
        // stage chunk g of V: bufu[c*128 + m2] = rn-f16 pair (v[c][2m2], v[c][2m2+1])
#pragma unroll
        for (int i = 0; i < 8; ++i) {
            const int c = wv * 8 + i;
            const float4 a = *reinterpret_cast<const float4*>(
                Vb + c * 2048 + g * 256 + lane * 4);
            uint2 w;
            w.x = pk_rn(a.x, a.y);
            w.y = pk_rn(a.z, a.w);
            *reinterpret_cast<uint2*>(&bufu[c * 128 + lane * 2]) = w;
        }
        __syncthreads();
        const unsigned int pa0 = p0pk[g * 2], pb0 = p0pk[g * 2 + 1];
        const unsigned int pa1 = p1pk[g * 2], pb1 = p1pk[g * 2 + 1];
#pragma unroll
        for (int c = 0; c < 32; ++c) {
            const uint2 vv = *reinterpret_cast<const uint2*>(&bufu[c * 128 + lane * 2]);
            acc0[c] = fdot2u(vv.x, pa0, acc0[c]);
            acc0[c] = fdot2u(vv.y, pb0, acc0[c]);
            acc1[c] = fdot2u(vv.x, pa1, acc1[c]);
            acc1[c] = fdot2u(vv.y, pb1, acc1[c]);
        }
        __syncthreads();
    }

    // Reduce-scatter across lanes -> lane holds channel c = lane&31; write O.
    const float o0 = rscat32(acc0, lane) * invd0;
    const float o1 = rscat32(acc1, lane) * invd1;
    const int r0 = n0 + wv * 2;
    if (lane < 32) {
        O[(bh * 2048 + r0) * 32 + lane]     = o0;
        O[(bh * 2048 + r0 + 1) * 32 + lane] = o1;
    }
}

// ---------------- Kernel D: output projection (512x512 GEMM per batch) ------
__global__ __launch_bounds__(256) void proj_out(const float* __restrict__ wproj,
                                                const float* __restrict__ ws,
                                                float* __restrict__ out) {
    const int tid = threadIdx.x;
    const int blk = blockIdx.x;
    const int st = blk & 7;
    const int ot = (blk >> 3) & 7;
    const int b  = blk >> 6;
    const int sbase = st * 128, obase = ot * 64;
    const float* O = ws + 3 * QSZ;

    __shared__ float At[32 * 132];   // [chn][s]
    __shared__ float Wt[32 * 68];    // [chn][o]

    float acc[4][8];
#pragma unroll
    for (int i = 0; i < 4; ++i)
#pragma unroll
        for (int j = 0; j < 8; ++j) acc[i][j] = 0.f;

    const int og = tid >> 4, sg = tid & 15;

    for (int cb = 0; cb < 16; ++cb) {     // c' block: c' = cb*32 + chn
        const int g = cb >> 3, head = cb & 7, bh = b * 8 + head;
        {   // stage A^T: A[c'][s] = O[bh][2s+g][chn]
            const int ss = tid >> 1, half = tid & 1;
            const float* op = O + ((bh * 2048) + (sbase + ss) * 2 + g) * 32 + half * 16;
#pragma unroll
            for (int j = 0; j < 4; ++j) {
                const float4 v = *reinterpret_cast<const float4*>(op + 4 * j);
                At[(half * 16 + 4 * j + 0) * 132 + ss] = v.x;
                At[(half * 16 + 4 * j + 1) * 132 + ss] = v.y;
                At[(half * 16 + 4 * j + 2) * 132 + ss] = v.z;
                At[(half * 16 + 4 * j + 3) * 132 + ss] = v.w;
            }
        }
        {   // stage W^T
            const int oo = tid >> 2, q = tid & 3;
#pragma unroll
            for (int jj = 0; jj < 2; ++jj) {
                const int chn = q * 8 + jj * 4;
                const float4 v = *reinterpret_cast<const float4*>(
                    wproj + (obase + oo) * 512 + cb * 32 + chn);
                Wt[(chn + 0) * 68 + oo] = v.x;
                Wt[(chn + 1) * 68 + oo] = v.y;
                Wt[(chn + 2) * 68 + oo] = v.z;
                Wt[(chn + 3) * 68 + oo] = v.w;
            }
        }
        __syncthreads();
#pragma unroll 8
        for (int chn = 0; chn < 32; ++chn) {
            const float4 wv = *reinterpret_cast<const float4*>(&Wt[chn * 68 + og * 4]);
            const float4 a0 = *reinterpret_cast<const float4*>(&At[chn * 132 + sg * 8]);
            const float4 a1 = *reinterpret_cast<const float4*>(&At[chn * 132 + sg * 8 + 4]);
            const float wj[4] = {wv.x, wv.y, wv.z, wv.w};
            const float aj[8] = {a0.x, a0.y, a0.z, a0.w, a1.x, a1.y, a1.z, a1.w};
#pragma unroll
            for (int i = 0; i < 4; ++i)
#pragma unroll
                for (int j = 0; j < 8; ++j) acc[i][j] += wj[i] * aj[j];
        }
        __syncthreads();
    }
#pragma unroll
    for (int i = 0; i < 4; ++i) {
        float* dst = out + (b * 512 + obase + og * 4 + i) * 1024 + sbase + sg * 8;
        *reinterpret_cast<float4*>(dst)     = make_float4(acc[i][0], acc[i][1], acc[i][2], acc[i][3]);
        *reinterpret_cast<float4*>(dst + 4) = make_float4(acc[i][4], acc[i][5], acc[i][6], acc[i][7]);
    }
}

extern "C" void kernel_launch(void* const* d_in, const int* in_sizes, int n_in,
                              void* d_out, int out_size, void* d_ws, size_t ws_size,
                              hipStream_t stream) {
    (void)in_sizes; (void)n_in; (void)out_size; (void)ws_size;
    const float* x     = (const float*)d_in[0];
    const float* wqkv  = (const float*)d_in[1];
    const float* wdw   = (const float*)d_in[2];
    const float* wproj = (const float*)d_in[3];
    const float* tempr = (const float*)d_in[4];
    float* ws  = (float*)d_ws;    // needs (4*QSZ + 512)*4B ~= 16.8 MB
    float* out = (float*)d_out;

    conv_qkv<<<3072, 256, 0, stream>>>(x, wqkv, wdw, ws);
    normfac<<<512, 256, 0, stream>>>(tempr, ws);
    attn_topk<<<4096, 256, 0, stream>>>(ws);
    proj_out<<<128, 256, 0, stream>>>(wproj, ws, out);
}